// Round 12
// baseline (2478.210 us; speedup 1.0000x reference)
//
#include <hip/hip_runtime.h>
#include <hip/hip_bf16.h>

// ---------------- problem constants ----------------
#define NN 500000
#define EE 1250000
#define NP 501760          // padded node count
#define NBLK 489           // scan blocks of 1024

typedef __attribute__((ext_vector_type(8))) short bf16x8;
typedef __attribute__((ext_vector_type(4))) float f32x4;

__device__ __forceinline__ float ngnn97_bf2f(unsigned short u) {
  return __uint_as_float(((unsigned int)u) << 16);
}
__device__ __forceinline__ unsigned short ngnn97_f2bf(float f) {
  union { __hip_bfloat16 b; unsigned short u; } cv;
  cv.b = __float2bfloat16(f);
  return cv.u;
}

// ---------------- diagnostic code writer (guard path only) ----------------
__global__ void ngnn97_code(float* __restrict__ out, float v) {
  if (threadIdx.x < 64) out[threadIdx.x] = v;
}

// ---------------- precompute folded weights (bf16, MFMA-B layout) ----------------
__global__ __launch_bounds__(256) void ngnn97_pre(
    const float* __restrict__ ggc, const float* __restrict__ wih,
    const float* __restrict__ whh, const float* __restrict__ bih,
    const float* __restrict__ bhh, const float* __restrict__ tfW,
    unsigned short* __restrict__ Ubt, float* __restrict__ Ub,
    unsigned short* __restrict__ Vbt) {
  int idx = blockIdx.x * 256 + threadIdx.x;
  if (idx < 163840) {                      // Ubt: 5*256*128
    int l = idx >> 15, r = idx & 32767;
    int n = r >> 7, k = r & 127;
    float v = 0.f;
    if (k < 64) {
      if (n < 192) {
        const float* gp = ggc + l * 4096 + k * 64;
        const float* wp = wih + l * 12288 + n * 64;
        float acc = 0.f;
#pragma unroll
        for (int t2 = 0; t2 < 64; t2++) acc = fmaf(gp[t2], wp[t2], acc);
        v = acc;
      }
    } else {
      int k2 = k - 64;
      if (n < 128) v = whh[l * 12288 + n * 64 + k2];
      else if (n >= 192) v = whh[l * 12288 + (n - 64) * 64 + k2];
    }
    Ubt[idx] = ngnn97_f2bf(v);
  } else if (idx < 163840 + 32768) {       // Vbt: 4*64*128 (= tfW flat)
    int i2 = idx - 163840;
    Vbt[i2] = ngnn97_f2bf(tfW[i2]);
  } else if (idx < 163840 + 32768 + 1280) { // Ub: 5*256
    int i2 = idx - 196608;
    int l = i2 >> 8, j = i2 & 255;
    float v;
    if (j < 128)      v = bih[l * 192 + j] + bhh[l * 192 + j];
    else if (j < 192) v = bih[l * 192 + j];
    else              v = bhh[l * 192 + j - 64];
    Ub[i2] = v;
  }
}

// ---------------- CSR build ----------------
__global__ __launch_bounds__(256) void ngnn97_hist(const int* __restrict__ dst, int* __restrict__ counts) {
  int e = blockIdx.x * 256 + threadIdx.x;
  if (e < EE) atomicAdd(&counts[dst[e]], 1);
}

__global__ __launch_bounds__(256) void ngnn97_red(const int* __restrict__ counts, int* __restrict__ bsum) {
  __shared__ int s[256];
  int t = threadIdx.x, base = blockIdx.x * 1024;
  int v = 0;
#pragma unroll
  for (int i = 0; i < 4; i++) v += counts[base + t + i * 256];
  s[t] = v; __syncthreads();
  for (int o = 128; o > 0; o >>= 1) { if (t < o) s[t] += s[t + o]; __syncthreads(); }
  if (t == 0) bsum[blockIdx.x] = s[0];
}

__global__ __launch_bounds__(512) void ngnn97_scan1(const int* __restrict__ bsum, int* __restrict__ boff) {
  __shared__ int s[512];
  int t = threadIdx.x;
  int v = (t < NBLK) ? bsum[t] : 0;
  s[t] = v; __syncthreads();
  for (int o = 1; o < 512; o <<= 1) {
    int a = (t >= o) ? s[t - o] : 0;
    __syncthreads(); s[t] += a; __syncthreads();
  }
  if (t < NBLK) boff[t] = s[t] - v;   // exclusive
}

__global__ __launch_bounds__(256) void ngnn97_scan2(const int* __restrict__ counts, const int* __restrict__ boff,
                                                    int* __restrict__ row_ptr, int* __restrict__ cursor) {
  __shared__ int s[256];
  int t = threadIdx.x, base = blockIdx.x * 1024;
  int4 c = *(const int4*)(counts + base + t * 4);
  int tsum = c.x + c.y + c.z + c.w;
  s[t] = tsum; __syncthreads();
  for (int o = 1; o < 256; o <<= 1) {
    int a = (t >= o) ? s[t - o] : 0;
    __syncthreads(); s[t] += a; __syncthreads();
  }
  int off = boff[blockIdx.x] + s[t] - tsum;
  int4 r;
  r.x = off; r.y = off + c.x; r.z = off + c.x + c.y; r.w = off + c.x + c.y + c.z;
  *(int4*)(row_ptr + base + t * 4) = r;
  *(int4*)(cursor + base + t * 4) = r;
}

__global__ __launch_bounds__(256) void ngnn97_fill(const int* __restrict__ src, const int* __restrict__ dst,
                                                   int* __restrict__ cursor, int* __restrict__ srcs) {
  int e = blockIdx.x * 256 + threadIdx.x;
  if (e < EE) {
    int pos = atomicAdd(&cursor[dst[e]], 1);
    srcs[pos] = src[e];
  }
}

// ---------------- node -> graph id precompute (uint8) ----------------
__global__ __launch_bounds__(256) void ngnn97_g8(const int* __restrict__ n2s, const int* __restrict__ s2g,
                                                 unsigned char* __restrict__ g8) {
  int idx = blockIdx.x * 256 + threadIdx.x;
  if (idx < NN) g8[idx] = (unsigned char)s2g[n2s[idx]];
}

// ---------------- layer-0 embedding (writes bf16 xh) ----------------
__global__ __launch_bounds__(256) void ngnn97_embed(const int* __restrict__ z, const float* __restrict__ tab,
                                                    unsigned short* __restrict__ xh) {
  int idx = blockIdx.x * 256 + threadIdx.x;
  int node = idx >> 4, c4 = (idx & 15) << 2;
  if (node < NN) {
    int zz = z[node];
    float4 v = *(const float4*)(tab + zz * 64 + c4);
    ushort4 q;
    q.x = ngnn97_f2bf(v.x); q.y = ngnn97_f2bf(v.y);
    q.z = ngnn97_f2bf(v.z); q.w = ngnn97_f2bf(v.w);
    *(ushort4*)(xh + (size_t)node * 64 + c4) = q;
  }
}

// ---------------- fused gather + GRU via MFMA (+ next-layer transform) ----------------
// Ping-pong: reads xh_old (all nodes final from prev layer), writes xh_new.
// Block = 128 nodes, 4 waves; wave w owns strip [nbase+32w, +32).
// Everything is strip-local -> ZERO barriers.
__global__ __launch_bounds__(256) void ngnn97_gru(
    const unsigned short* __restrict__ xh_old, unsigned short* __restrict__ xh_new,
    const int* __restrict__ rowp, const int* __restrict__ srcs,
    const unsigned short* __restrict__ Ubt, const float* __restrict__ Ub,
    const unsigned short* __restrict__ Vbt, const float* __restrict__ tfb,
    const int* __restrict__ z, const float* __restrict__ ztab,
    int do_transform) {
  __shared__ unsigned short Abuf[128 * 136];   // 128 rows x (128 + pad 8) bf16, 34.8 KB
  const int t = threadIdx.x;
  const int lane = t & 63, w = t >> 6;
  const int ncol = lane & 15, quad = lane >> 4;
  const int nbase = blockIdx.x * 128;
  const int strip = 32 * w;

  // ---- stage xh_old rows of this strip -> Abuf cols 64..127 ----
#pragma unroll
  for (int i = 0; i < 8; i++) {
    int chunk = i * 64 + lane;               // 512 chunks = 32 rows x 16 ushort4
    int r2 = chunk >> 4, c4 = (chunk & 15) << 2;
    int node = nbase + strip + r2;
    ushort4 qx = make_ushort4(0, 0, 0, 0);
    if (node < NN) qx = *(const ushort4*)(xh_old + (size_t)node * 64 + c4);
    *(ushort4*)(Abuf + (strip + r2) * 136 + 64 + c4) = qx;
  }

  // ---- gather neighbor sums for this strip -> Abuf cols 0..63 ----
  {
    int li = lane & 31;
    int bq = rowp[nbase + strip + li];       // 32 lane-parallel CSR bounds
    int eq = rowp[nbase + strip + li + 1];
#pragma unroll 2
    for (int i = 0; i < 32; i++) {
      int b = __shfl(bq, i), e1 = __shfl(eq, i);
      float acc = 0.f;
      for (int p = b; p < e1; p++) {
        int s = srcs[p];                     // wave-broadcast load
        acc += ngnn97_bf2f(xh_old[(size_t)s * 64 + lane]);
      }
      Abuf[(strip + i) * 136 + lane] = ngnn97_f2bf(acc);
    }
  }

  // ---- A-frags: 2 m-tiles x 4 K-chunks ----
  bf16x8 afr[2][4];
#pragma unroll
  for (int mm = 0; mm < 2; mm++) {
    const unsigned short* ap = Abuf + (strip + mm * 16 + ncol) * 136 + quad * 8;
#pragma unroll
    for (int kc = 0; kc < 4; kc++) afr[mm][kc] = *(const bf16x8*)(ap + kc * 32);
  }

  // ---- gate GEMM + GRU update; xn -> Abuf cols 0..63 ----
#pragma unroll
  for (int c = 0; c < 4; c++) {
    f32x4 aR[2], aZ[2], aN[2], aH[2];
#pragma unroll
    for (int mm = 0; mm < 2; mm++) {
      aR[mm] = (f32x4){0.f, 0.f, 0.f, 0.f}; aZ[mm] = aR[mm];
      aN[mm] = aR[mm]; aH[mm] = aR[mm];
    }
#pragma unroll
    for (int kc = 0; kc < 4; kc++) {
      const unsigned short* ub = Ubt + (size_t)(c * 16 + ncol) * 128 + quad * 8 + kc * 32;
      bf16x8 bR = *(const bf16x8*)(ub);
      bf16x8 bZ = *(const bf16x8*)(ub + 64 * 128);
      bf16x8 bX = (kc < 2) ? *(const bf16x8*)(ub + 128 * 128)
                           : *(const bf16x8*)(ub + 192 * 128);
#pragma unroll
      for (int mm = 0; mm < 2; mm++) {
        aR[mm] = __builtin_amdgcn_mfma_f32_16x16x32_bf16(afr[mm][kc], bR, aR[mm], 0, 0, 0);
        aZ[mm] = __builtin_amdgcn_mfma_f32_16x16x32_bf16(afr[mm][kc], bZ, aZ[mm], 0, 0, 0);
        if (kc < 2) aN[mm] = __builtin_amdgcn_mfma_f32_16x16x32_bf16(afr[mm][kc], bX, aN[mm], 0, 0, 0);
        else        aH[mm] = __builtin_amdgcn_mfma_f32_16x16x32_bf16(afr[mm][kc], bX, aH[mm], 0, 0, 0);
      }
    }
    int j = c * 16 + ncol;
    float bRs = Ub[j], bZs = Ub[64 + j], bNs = Ub[128 + j], bHs = Ub[192 + j];
#pragma unroll
    for (int mm = 0; mm < 2; mm++)
#pragma unroll
      for (int r = 0; r < 4; r++) {
        int row = strip + mm * 16 + quad * 4 + r;
        float R = aR[mm][r] + bRs, Z = aZ[mm][r] + bZs;
        float Nv = aN[mm][r] + bNs, H = aH[mm][r] + bHs;
        float rg = 1.f / (1.f + __expf(-R));
        float ug = 1.f / (1.f + __expf(-Z));
        float e2 = __expf(2.f * (Nv + rg * H));
        float nn2 = 1.f - 2.f / (e2 + 1.f);       // tanh via fast exp (saturates safely)
        float xo = ngnn97_bf2f(Abuf[row * 136 + 64 + j]);
        Abuf[row * 136 + j] = ngnn97_f2bf((1.f - ug) * nn2 + ug * xo);
      }
  }

  if (do_transform) {
    // ---- embed fill: strip rows, cols 64..127 ----
#pragma unroll 4
    for (int i = 0; i < 32; i++) {
      int row = strip + i;
      int node = nbase + row;
      int zz = (node < NN) ? z[node] : 0;
      Abuf[row * 136 + 64 + lane] = ngnn97_f2bf(ztab[zz * 64 + lane]);
    }
    bf16x8 afr2[2][4];
#pragma unroll
    for (int mm = 0; mm < 2; mm++) {
      const unsigned short* ap2 = Abuf + (strip + mm * 16 + ncol) * 136 + quad * 8;
#pragma unroll
      for (int kc = 0; kc < 4; kc++) afr2[mm][kc] = *(const bf16x8*)(ap2 + kc * 32);
    }
#pragma unroll
    for (int c2 = 0; c2 < 4; c2++) {
      f32x4 acc[2];
      acc[0] = (f32x4){0.f, 0.f, 0.f, 0.f}; acc[1] = acc[0];
#pragma unroll
      for (int kc = 0; kc < 4; kc++) {
        bf16x8 bV = *(const bf16x8*)(Vbt + (size_t)(c2 * 16 + ncol) * 128 + quad * 8 + kc * 32);
        acc[0] = __builtin_amdgcn_mfma_f32_16x16x32_bf16(afr2[0][kc], bV, acc[0], 0, 0, 0);
        acc[1] = __builtin_amdgcn_mfma_f32_16x16x32_bf16(afr2[1][kc], bV, acc[1], 0, 0, 0);
      }
      int j = c2 * 16 + ncol;
      float bt = tfb[j];
#pragma unroll
      for (int mm = 0; mm < 2; mm++)
#pragma unroll
        for (int r = 0; r < 4; r++) {
          int row = strip + mm * 16 + quad * 4 + r;
          Abuf[row * 136 + j] = ngnn97_f2bf(acc[mm][r] + bt);
        }
    }
  }

  // ---- coalesced store: Abuf cols 0..63 (strip) -> xh_new ----
#pragma unroll
  for (int i = 0; i < 8; i++) {
    int chunk = i * 64 + lane;
    int r2 = chunk >> 4, c4 = (chunk & 15) << 2;
    int row = strip + r2;
    int node = nbase + row;
    if (node < NN)
      *(ushort4*)(xh_new + (size_t)node * 64 + c4) = *(const ushort4*)(Abuf + row * 136 + c4);
  }
}

// ---------------- pooling stage 1: 256 nodes/block, partial sums into 256 slots ----------------
__global__ __launch_bounds__(256) void ngnn97_pool(const unsigned short* __restrict__ xh,
                                                   const unsigned char* __restrict__ g8,
                                                   float* __restrict__ gpart) {
  __shared__ float gacc[64][64];
  int t = threadIdx.x, w = t >> 6, lane = t & 63;
  for (int i = t; i < 4096; i += 256) ((float*)gacc)[i] = 0.f;
  __syncthreads();
  int base = blockIdx.x * 256;
#pragma unroll 4
  for (int it = 0; it < 64; it++) {
    int node = base + it * 4 + w;
    if (node < NN) {
      int g = g8[node];
      atomicAdd(&gacc[g][lane], ngnn97_bf2f(xh[(size_t)node * 64 + lane]));
    }
  }
  __syncthreads();
  float* slot = gpart + (size_t)(blockIdx.x & 255) * 4096;
  for (int i = t; i < 4096; i += 256) {
    float v = ((float*)gacc)[i];
    if (v != 0.f) atomicAdd(&slot[i], v);
  }
}

// ---------------- pooling stage 2: fold 256 slots -> gpool ----------------
__global__ __launch_bounds__(256) void ngnn97_reduce(const float* __restrict__ gpart,
                                                     float* __restrict__ gpool) {
  int i = blockIdx.x * 256 + threadIdx.x;    // 0..4095
  float s = 0.f;
#pragma unroll 8
  for (int k = 0; k < 256; k++) s += gpart[(size_t)k * 4096 + i];
  gpool[i] = s;
}

// ---------------- MLP head (output: float32 [G,1]) ----------------
__global__ __launch_bounds__(256) void ngnn97_head(
    const float* __restrict__ gpool,
    const float* __restrict__ W1, const float* __restrict__ b1,
    const float* __restrict__ W2, const float* __restrict__ b2,
    const float* __restrict__ W3, const float* __restrict__ b3,
    float* __restrict__ out) {
  __shared__ float gp[4096];
  __shared__ float h1[2048];
  __shared__ float h2[1024];
  int t = threadIdx.x;
  for (int i = t; i < 4096; i += 256) gp[i] = gpool[i];
  __syncthreads();
  for (int i = t; i < 2048; i += 256) {
    int g = i >> 5, o = i & 31;
    float a = b1[o];
    for (int d = 0; d < 64; d++) a = fmaf(gp[g * 64 + d], W1[o * 64 + d], a);
    h1[i] = (a > 0.f) ? a : (__expf(a) - 1.f);
  }
  __syncthreads();
  for (int i = t; i < 1024; i += 256) {
    int g = i >> 4, o = i & 15;
    float a = b2[o];
    for (int d = 0; d < 32; d++) a = fmaf(h1[g * 32 + d], W2[o * 32 + d], a);
    h2[i] = (a > 0.f) ? a : (__expf(a) - 1.f);
  }
  __syncthreads();
  if (t < 64) {
    float a = b3[0];
    for (int d = 0; d < 16; d++) a = fmaf(h2[t * 16 + d], W3[d], a);
    out[t] = a;
  }
}

// ---------------- workspace layout (byte offsets) ----------------
// Ping-pong xh0/xh1 (aggx eliminated). 144 MB total, under proven 203.8 MB.
#define OFF_XH0   ((size_t)0)                          // N*64 bf16 = 64,000,000
#define OFF_XH1   ((size_t)64000000)                   // N*64 bf16 = 64,000,000
#define OFF_CNT   ((size_t)128000000)                  // NP int
#define OFF_ROW   (OFF_CNT + (size_t)NP * 4)
#define OFF_CUR   (OFF_ROW + (size_t)NP * 4)
#define OFF_SRC   (OFF_CUR + (size_t)NP * 4)           // E int
#define OFF_BSUM  (OFF_SRC + (size_t)EE * 4)
#define OFF_BOFF  (OFF_BSUM + (size_t)2048)
#define OFF_U     (OFF_BOFF + (size_t)2048)            // Ubt bf16 5*256*128
#define OFF_UB    (OFF_U + (size_t)327680)             // Ub f32 5*256
#define OFF_V     (OFF_UB + (size_t)5120)              // Vbt bf16 4*64*128
#define OFF_GP    (OFF_V + (size_t)65536)              // gpool 64*64 f32
#define OFF_G8    (OFF_GP + (size_t)16384)             // N uint8 (padded)
#define OFF_GPART (OFF_G8 + (size_t)500736)            // 256*4096 f32 = 4 MB
#define WS_NEED   (OFF_GPART + (size_t)4194304)        // = 144,151,360

extern "C" void kernel_launch(void* const* d_in, const int* in_sizes, int n_in,
                              void* d_out, int out_size, void* d_ws, size_t ws_size,
                              hipStream_t stream) {
  float* out = (float*)d_out;   // reference output is float32 [G,1]
  if (ws_size < WS_NEED) {
    ngnn97_code<<<1, 64, 0, stream>>>(out, 7.0f);
    return;
  }

  const int* z    = (const int*)d_in[0];
  const int* ei   = (const int*)d_in[1];
  const int* n2s  = (const int*)d_in[2];
  const int* s2g  = (const int*)d_in[3];
  const float* ztab = (const float*)d_in[4];
  const float* tfW  = (const float*)d_in[5];
  const float* tfb  = (const float*)d_in[6];
  const float* ggc  = (const float*)d_in[7];
  const float* wih  = (const float*)d_in[8];
  const float* whh  = (const float*)d_in[9];
  const float* bih  = (const float*)d_in[10];
  const float* bhh  = (const float*)d_in[11];
  const float* W1   = (const float*)d_in[12];
  const float* b1   = (const float*)d_in[13];
  const float* W2   = (const float*)d_in[14];
  const float* b2   = (const float*)d_in[15];
  const float* W3   = (const float*)d_in[16];
  const float* b3   = (const float*)d_in[17];

  char* ws = (char*)d_ws;
  unsigned short* xh0    = (unsigned short*)(ws + OFF_XH0);
  unsigned short* xh1    = (unsigned short*)(ws + OFF_XH1);
  int*            counts = (int*)(ws + OFF_CNT);
  int*            rowp   = (int*)(ws + OFF_ROW);
  int*            curs   = (int*)(ws + OFF_CUR);
  int*            srcs   = (int*)(ws + OFF_SRC);
  int*            bsum   = (int*)(ws + OFF_BSUM);
  int*            boff   = (int*)(ws + OFF_BOFF);
  unsigned short* Ubt    = (unsigned short*)(ws + OFF_U);
  float*          Ub     = (float*)(ws + OFF_UB);
  unsigned short* Vbt    = (unsigned short*)(ws + OFF_V);
  float*          gpool  = (float*)(ws + OFF_GP);
  unsigned char*  g8     = (unsigned char*)(ws + OFF_G8);
  float*          gpart  = (float*)(ws + OFF_GPART);

  hipMemsetAsync(counts, 0, (size_t)NP * 4, stream);
  hipMemsetAsync(gpart, 0, (size_t)4194304, stream);

  ngnn97_pre<<<774, 256, 0, stream>>>(ggc, wih, whh, bih, bhh, tfW, Ubt, Ub, Vbt);
  ngnn97_g8<<<(NN + 255) / 256, 256, 0, stream>>>(n2s, s2g, g8);

  // CSR by dst
  const int* srcp = ei;
  const int* dstp = ei + EE;
  ngnn97_hist<<<(EE + 255) / 256, 256, 0, stream>>>(dstp, counts);
  ngnn97_red<<<NBLK, 256, 0, stream>>>(counts, bsum);
  ngnn97_scan1<<<1, 512, 0, stream>>>(bsum, boff);
  ngnn97_scan2<<<NBLK, 256, 0, stream>>>(counts, boff, rowp, curs);
  ngnn97_fill<<<(EE + 255) / 256, 256, 0, stream>>>(srcp, dstp, curs, srcs);

  ngnn97_embed<<<(NN * 16 + 255) / 256, 256, 0, stream>>>(z, ztab, xh0);

  unsigned short* xc = xh0;
  unsigned short* xn2 = xh1;
  for (int l = 0; l < 5; l++) {
    ngnn97_gru<<<(NN + 127) / 128, 256, 0, stream>>>(
        xc, xn2, rowp, srcs,
        Ubt + (size_t)l * 32768, Ub + (size_t)l * 256,
        Vbt + (size_t)(l < 4 ? l : 0) * 8192, tfb + (size_t)(l < 4 ? l : 0) * 64,
        z, ztab + (size_t)(l < 4 ? l + 1 : 0) * 6400, (l < 4) ? 1 : 0);
    unsigned short* tmp = xc; xc = xn2; xn2 = tmp;
  }
  // final state is in xc (= xh1 after 5 swaps)

  ngnn97_pool<<<(NN + 255) / 256, 256, 0, stream>>>(xc, g8, gpart);
  ngnn97_reduce<<<16, 256, 0, stream>>>(gpart, gpool);
  ngnn97_head<<<1, 256, 0, stream>>>(gpool, W1, b1, W2, b2, W3, b3, out);
}

// Round 13
// 1372.595 us; speedup vs baseline: 1.8055x; 1.8055x over previous
//
#include <hip/hip_runtime.h>
#include <hip/hip_bf16.h>

// ---------------- problem constants ----------------
#define NN 500000
#define EE 1250000
#define NP 501760          // padded node count
#define NBLK 489           // scan blocks of 1024

typedef __attribute__((ext_vector_type(8))) short bf16x8;
typedef __attribute__((ext_vector_type(4))) float f32x4;

__device__ __forceinline__ float ngnn97_bf2f(unsigned short u) {
  return __uint_as_float(((unsigned int)u) << 16);
}
__device__ __forceinline__ unsigned short ngnn97_f2bf(float f) {
  union { __hip_bfloat16 b; unsigned short u; } cv;
  cv.b = __float2bfloat16(f);
  return cv.u;
}

// ---------------- diagnostic code writer (guard path only) ----------------
__global__ void ngnn97_code(float* __restrict__ out, float v) {
  if (threadIdx.x < 64) out[threadIdx.x] = v;
}

// ---------------- precompute folded weights (bf16, MFMA-B layout) + bf16 ztab ----------------
__global__ __launch_bounds__(256) void ngnn97_pre(
    const float* __restrict__ ggc, const float* __restrict__ wih,
    const float* __restrict__ whh, const float* __restrict__ bih,
    const float* __restrict__ bhh, const float* __restrict__ tfW,
    const float* __restrict__ ztab,
    unsigned short* __restrict__ Ubt, float* __restrict__ Ub,
    unsigned short* __restrict__ Vbt, unsigned short* __restrict__ ztabh) {
  int idx = blockIdx.x * 256 + threadIdx.x;
  if (idx < 163840) {                      // Ubt: 5*256*128
    int l = idx >> 15, r = idx & 32767;
    int n = r >> 7, k = r & 127;
    float v = 0.f;
    if (k < 64) {
      if (n < 192) {
        const float* gp = ggc + l * 4096 + k * 64;
        const float* wp = wih + l * 12288 + n * 64;
        float acc = 0.f;
#pragma unroll
        for (int t2 = 0; t2 < 64; t2++) acc = fmaf(gp[t2], wp[t2], acc);
        v = acc;
      }
    } else {
      int k2 = k - 64;
      if (n < 128) v = whh[l * 12288 + n * 64 + k2];
      else if (n >= 192) v = whh[l * 12288 + (n - 64) * 64 + k2];
    }
    Ubt[idx] = ngnn97_f2bf(v);
  } else if (idx < 196608) {               // Vbt: 4*64*128 (= tfW flat)
    int i2 = idx - 163840;
    Vbt[i2] = ngnn97_f2bf(tfW[i2]);
  } else if (idx < 197888) {               // Ub: 5*256
    int i2 = idx - 196608;
    int l = i2 >> 8, j = i2 & 255;
    float v;
    if (j < 128)      v = bih[l * 192 + j] + bhh[l * 192 + j];
    else if (j < 192) v = bih[l * 192 + j];
    else              v = bhh[l * 192 + j - 64];
    Ub[i2] = v;
  } else if (idx < 229888) {               // ztabh: 5*100*64 bf16
    int i2 = idx - 197888;
    ztabh[i2] = ngnn97_f2bf(ztab[i2]);
  }
}

// ---------------- CSR build ----------------
__global__ __launch_bounds__(256) void ngnn97_hist(const int* __restrict__ dst, int* __restrict__ counts) {
  int e = blockIdx.x * 256 + threadIdx.x;
  if (e < EE) atomicAdd(&counts[dst[e]], 1);
}

__global__ __launch_bounds__(256) void ngnn97_red(const int* __restrict__ counts, int* __restrict__ bsum) {
  __shared__ int s[256];
  int t = threadIdx.x, base = blockIdx.x * 1024;
  int v = 0;
#pragma unroll
  for (int i = 0; i < 4; i++) v += counts[base + t + i * 256];
  s[t] = v; __syncthreads();
  for (int o = 128; o > 0; o >>= 1) { if (t < o) s[t] += s[t + o]; __syncthreads(); }
  if (t == 0) bsum[blockIdx.x] = s[0];
}

__global__ __launch_bounds__(512) void ngnn97_scan1(const int* __restrict__ bsum, int* __restrict__ boff) {
  __shared__ int s[512];
  int t = threadIdx.x;
  int v = (t < NBLK) ? bsum[t] : 0;
  s[t] = v; __syncthreads();
  for (int o = 1; o < 512; o <<= 1) {
    int a = (t >= o) ? s[t - o] : 0;
    __syncthreads(); s[t] += a; __syncthreads();
  }
  if (t < NBLK) boff[t] = s[t] - v;   // exclusive
}

__global__ __launch_bounds__(256) void ngnn97_scan2(const int* __restrict__ counts, const int* __restrict__ boff,
                                                    int* __restrict__ row_ptr, int* __restrict__ cursor) {
  __shared__ int s[256];
  int t = threadIdx.x, base = blockIdx.x * 1024;
  int4 c = *(const int4*)(counts + base + t * 4);
  int tsum = c.x + c.y + c.z + c.w;
  s[t] = tsum; __syncthreads();
  for (int o = 1; o < 256; o <<= 1) {
    int a = (t >= o) ? s[t - o] : 0;
    __syncthreads(); s[t] += a; __syncthreads();
  }
  int off = boff[blockIdx.x] + s[t] - tsum;
  int4 r;
  r.x = off; r.y = off + c.x; r.z = off + c.x + c.y; r.w = off + c.x + c.y + c.z;
  *(int4*)(row_ptr + base + t * 4) = r;
  *(int4*)(cursor + base + t * 4) = r;
}

__global__ __launch_bounds__(256) void ngnn97_fill(const int* __restrict__ src, const int* __restrict__ dst,
                                                   int* __restrict__ cursor, int* __restrict__ srcs) {
  int e = blockIdx.x * 256 + threadIdx.x;
  if (e < EE) {
    int pos = atomicAdd(&cursor[dst[e]], 1);
    srcs[pos] = src[e];
  }
}

// ---------------- node -> graph id precompute (uint8) ----------------
__global__ __launch_bounds__(256) void ngnn97_g8(const int* __restrict__ n2s, const int* __restrict__ s2g,
                                                 unsigned char* __restrict__ g8) {
  int idx = blockIdx.x * 256 + threadIdx.x;
  if (idx < NN) g8[idx] = (unsigned char)s2g[n2s[idx]];
}

// ---------------- layer-0 embedding (writes bf16 xh) ----------------
__global__ __launch_bounds__(256) void ngnn97_embed(const int* __restrict__ z, const float* __restrict__ tab,
                                                    unsigned short* __restrict__ xh) {
  int idx = blockIdx.x * 256 + threadIdx.x;
  int node = idx >> 4, c4 = (idx & 15) << 2;
  if (node < NN) {
    int zz = z[node];
    float4 v = *(const float4*)(tab + zz * 64 + c4);
    ushort4 q;
    q.x = ngnn97_f2bf(v.x); q.y = ngnn97_f2bf(v.y);
    q.z = ngnn97_f2bf(v.z); q.w = ngnn97_f2bf(v.w);
    *(ushort4*)(xh + (size_t)node * 64 + c4) = q;
  }
}

// ---------------- neighbor aggregation: 8 nodes/wave, 8 lanes x bf16x8 per node ----------------
// 8 independent gather chains per wave -> 8x the memory-level parallelism of 1-node/wave.
__global__ __launch_bounds__(256) void ngnn97_agg(const unsigned short* __restrict__ xh,
                                                  const int* __restrict__ row_ptr,
                                                  const int* __restrict__ row_end, const int* __restrict__ srcs,
                                                  unsigned short* __restrict__ aggx) {
  int t = threadIdx.x;
  int wv = t >> 6, lane = t & 63;
  int grp = lane >> 3, sub = lane & 7;
  int node = blockIdx.x * 32 + wv * 8 + grp;
  if (node >= NN) return;
  int b = row_ptr[node], e = row_end[node];
  float acc[8];
#pragma unroll
  for (int i = 0; i < 8; i++) acc[i] = 0.f;
  for (int p = b; p < e; p++) {
    int s = srcs[p];
    bf16x8 v = *(const bf16x8*)(xh + (size_t)s * 64 + sub * 8);
#pragma unroll
    for (int i = 0; i < 8; i++) acc[i] += ngnn97_bf2f((unsigned short)v[i]);
  }
  bf16x8 ov;
#pragma unroll
  for (int i = 0; i < 8; i++) ov[i] = (short)ngnn97_f2bf(acc[i]);
  *(bf16x8*)(aggx + (size_t)node * 64 + sub * 8) = ov;
}

// ---------------- GRU via MFMA (+ next-layer transform) ----------------
// Block = 128 nodes, 4 waves; wave w owns strip [nbase+32w, +32) -> ZERO barriers.
// aggx A-frags load DIRECTLY from global; only xh is staged in LDS (xo + frags).
// ze A-frags load directly from precomputed bf16 ztabh. LDS = 128x72x2 = 18.4 KB.
__global__ __launch_bounds__(256) void ngnn97_gru(
    unsigned short* __restrict__ xh, const unsigned short* __restrict__ aggx,
    const unsigned short* __restrict__ Ubt, const float* __restrict__ Ub,
    const unsigned short* __restrict__ Vbt, const float* __restrict__ tfb,
    const int* __restrict__ z, const unsigned short* __restrict__ ztabh,
    int do_transform) {
  __shared__ unsigned short Abuf[128 * 72];    // xh strip staging + xn scratch
  const int t = threadIdx.x;
  const int lane = t & 63, w = t >> 6;
  const int ncol = lane & 15, quad = lane >> 4;
  const int nbase = blockIdx.x * 128;
  const int strip = 32 * w;

  // ---- stage xh strip rows -> Abuf cols 0..63 (strip-local) ----
#pragma unroll
  for (int i = 0; i < 8; i++) {
    int chunk = i * 64 + lane;                 // 512 = 32 rows x 16 ushort4
    int r2 = chunk >> 4, c4 = (chunk & 15) << 2;
    int node = nbase + strip + r2;
    ushort4 qx = make_ushort4(0, 0, 0, 0);
    if (node < NN) qx = *(const ushort4*)(xh + (size_t)node * 64 + c4);
    *(ushort4*)(Abuf + (strip + r2) * 72 + c4) = qx;
  }

  // ---- A-frags: aggx half direct-global, xh half from LDS ----
  bf16x8 afrA[2][2], afrX[2][2];
#pragma unroll
  for (int mm = 0; mm < 2; mm++) {
    int node = nbase + strip + mm * 16 + ncol;
#pragma unroll
    for (int kc = 0; kc < 2; kc++) {
      bf16x8 va = (bf16x8){0, 0, 0, 0, 0, 0, 0, 0};
      if (node < NN) va = *(const bf16x8*)(aggx + (size_t)node * 64 + quad * 8 + kc * 32);
      afrA[mm][kc] = va;
      afrX[mm][kc] = *(const bf16x8*)(Abuf + (strip + mm * 16 + ncol) * 72 + quad * 8 + kc * 32);
    }
  }

  // ---- gate GEMM + GRU update; xn overwrites Abuf cols 0..63 ----
#pragma unroll
  for (int c = 0; c < 4; c++) {
    f32x4 aR[2], aZ[2], aN[2], aH[2];
#pragma unroll
    for (int mm = 0; mm < 2; mm++) {
      aR[mm] = (f32x4){0.f, 0.f, 0.f, 0.f}; aZ[mm] = aR[mm];
      aN[mm] = aR[mm]; aH[mm] = aR[mm];
    }
#pragma unroll
    for (int kc = 0; kc < 4; kc++) {
      const unsigned short* ub = Ubt + (size_t)(c * 16 + ncol) * 128 + quad * 8 + kc * 32;
      bf16x8 bR = *(const bf16x8*)(ub);
      bf16x8 bZ = *(const bf16x8*)(ub + 64 * 128);
      bf16x8 bX = (kc < 2) ? *(const bf16x8*)(ub + 128 * 128)
                           : *(const bf16x8*)(ub + 192 * 128);
#pragma unroll
      for (int mm = 0; mm < 2; mm++) {
        bf16x8 a = (kc < 2) ? afrA[mm][kc] : afrX[mm][kc - 2];
        aR[mm] = __builtin_amdgcn_mfma_f32_16x16x32_bf16(a, bR, aR[mm], 0, 0, 0);
        aZ[mm] = __builtin_amdgcn_mfma_f32_16x16x32_bf16(a, bZ, aZ[mm], 0, 0, 0);
        if (kc < 2) aN[mm] = __builtin_amdgcn_mfma_f32_16x16x32_bf16(a, bX, aN[mm], 0, 0, 0);
        else        aH[mm] = __builtin_amdgcn_mfma_f32_16x16x32_bf16(a, bX, aH[mm], 0, 0, 0);
      }
    }
    int j = c * 16 + ncol;
    float bRs = Ub[j], bZs = Ub[64 + j], bNs = Ub[128 + j], bHs = Ub[192 + j];
#pragma unroll
    for (int mm = 0; mm < 2; mm++)
#pragma unroll
      for (int r = 0; r < 4; r++) {
        int row = strip + mm * 16 + quad * 4 + r;
        float R = aR[mm][r] + bRs, Z = aZ[mm][r] + bZs;
        float Nv = aN[mm][r] + bNs, H = aH[mm][r] + bHs;
        float rg = 1.f / (1.f + __expf(-R));
        float ug = 1.f / (1.f + __expf(-Z));
        float e2 = __expf(2.f * (Nv + rg * H));
        float nn2 = 1.f - 2.f / (e2 + 1.f);    // tanh via fast exp (saturates safely)
        float xo = ngnn97_bf2f(Abuf[row * 72 + j]);
        Abuf[row * 72 + j] = ngnn97_f2bf((1.f - ug) * nn2 + ug * xo);
      }
  }

  if (do_transform) {
    // ---- A2-frags: xn from LDS, ze direct from bf16 ztab ----
    bf16x8 afrN[2][2], afrE[2][2];
#pragma unroll
    for (int mm = 0; mm < 2; mm++) {
      int node = nbase + strip + mm * 16 + ncol;
      int zz = (node < NN) ? z[node] : 0;
#pragma unroll
      for (int kc = 0; kc < 2; kc++) {
        afrN[mm][kc] = *(const bf16x8*)(Abuf + (strip + mm * 16 + ncol) * 72 + quad * 8 + kc * 32);
        afrE[mm][kc] = *(const bf16x8*)(ztabh + zz * 64 + quad * 8 + kc * 32);
      }
    }
    // ---- transform GEMM -> Abuf cols 0..63 ----
#pragma unroll
    for (int c2 = 0; c2 < 4; c2++) {
      f32x4 acc[2];
      acc[0] = (f32x4){0.f, 0.f, 0.f, 0.f}; acc[1] = acc[0];
#pragma unroll
      for (int kc = 0; kc < 4; kc++) {
        bf16x8 bV = *(const bf16x8*)(Vbt + (size_t)(c2 * 16 + ncol) * 128 + quad * 8 + kc * 32);
#pragma unroll
        for (int mm = 0; mm < 2; mm++) {
          bf16x8 a = (kc < 2) ? afrN[mm][kc] : afrE[mm][kc - 2];
          acc[mm] = __builtin_amdgcn_mfma_f32_16x16x32_bf16(a, bV, acc[mm], 0, 0, 0);
        }
      }
      int j = c2 * 16 + ncol;
      float bt = tfb[j];
#pragma unroll
      for (int mm = 0; mm < 2; mm++)
#pragma unroll
        for (int r = 0; r < 4; r++) {
          int row = strip + mm * 16 + quad * 4 + r;
          Abuf[row * 72 + j] = ngnn97_f2bf(acc[mm][r] + bt);
        }
    }
  }

  // ---- coalesced store: Abuf cols 0..63 (strip) -> xh (in place; agg consumed old xh) ----
#pragma unroll
  for (int i = 0; i < 8; i++) {
    int chunk = i * 64 + lane;
    int r2 = chunk >> 4, c4 = (chunk & 15) << 2;
    int node = nbase + strip + r2;
    if (node < NN)
      *(ushort4*)(xh + (size_t)node * 64 + c4) = *(const ushort4*)(Abuf + (strip + r2) * 72 + c4);
  }
}

// ---------------- pooling stage 1: 256 nodes/block, partial sums into 256 slots ----------------
__global__ __launch_bounds__(256) void ngnn97_pool(const unsigned short* __restrict__ xh,
                                                   const unsigned char* __restrict__ g8,
                                                   float* __restrict__ gpart) {
  __shared__ float gacc[64][64];
  int t = threadIdx.x, w = t >> 6, lane = t & 63;
  for (int i = t; i < 4096; i += 256) ((float*)gacc)[i] = 0.f;
  __syncthreads();
  int base = blockIdx.x * 256;
#pragma unroll 4
  for (int it = 0; it < 64; it++) {
    int node = base + it * 4 + w;
    if (node < NN) {
      int g = g8[node];
      atomicAdd(&gacc[g][lane], ngnn97_bf2f(xh[(size_t)node * 64 + lane]));
    }
  }
  __syncthreads();
  float* slot = gpart + (size_t)(blockIdx.x & 255) * 4096;
  for (int i = t; i < 4096; i += 256) {
    float v = ((float*)gacc)[i];
    if (v != 0.f) atomicAdd(&slot[i], v);
  }
}

// ---------------- pooling stage 2: fold 256 slots -> gpool ----------------
__global__ __launch_bounds__(256) void ngnn97_reduce(const float* __restrict__ gpart,
                                                     float* __restrict__ gpool) {
  int i = blockIdx.x * 256 + threadIdx.x;    // 0..4095
  float s = 0.f;
#pragma unroll 8
  for (int k = 0; k < 256; k++) s += gpart[(size_t)k * 4096 + i];
  gpool[i] = s;
}

// ---------------- MLP head (output: float32 [G,1]) ----------------
__global__ __launch_bounds__(256) void ngnn97_head(
    const float* __restrict__ gpool,
    const float* __restrict__ W1, const float* __restrict__ b1,
    const float* __restrict__ W2, const float* __restrict__ b2,
    const float* __restrict__ W3, const float* __restrict__ b3,
    float* __restrict__ out) {
  __shared__ float gp[4096];
  __shared__ float h1[2048];
  __shared__ float h2[1024];
  int t = threadIdx.x;
  for (int i = t; i < 4096; i += 256) gp[i] = gpool[i];
  __syncthreads();
  for (int i = t; i < 2048; i += 256) {
    int g = i >> 5, o = i & 31;
    float a = b1[o];
    for (int d = 0; d < 64; d++) a = fmaf(gp[g * 64 + d], W1[o * 64 + d], a);
    h1[i] = (a > 0.f) ? a : (__expf(a) - 1.f);
  }
  __syncthreads();
  for (int i = t; i < 1024; i += 256) {
    int g = i >> 4, o = i & 15;
    float a = b2[o];
    for (int d = 0; d < 32; d++) a = fmaf(h1[g * 32 + d], W2[o * 32 + d], a);
    h2[i] = (a > 0.f) ? a : (__expf(a) - 1.f);
  }
  __syncthreads();
  if (t < 64) {
    float a = b3[0];
    for (int d = 0; d < 16; d++) a = fmaf(h2[t * 16 + d], W3[d], a);
    out[t] = a;
  }
}

// ---------------- workspace layout (byte offsets) ----------------
#define OFF_XH    ((size_t)0)                          // N*64 bf16 = 64,000,000
#define OFF_AGG   ((size_t)64000000)                   // N*64 bf16 = 64,000,000
#define OFF_CNT   ((size_t)128000000)                  // NP int
#define OFF_ROW   (OFF_CNT + (size_t)NP * 4)
#define OFF_CUR   (OFF_ROW + (size_t)NP * 4)
#define OFF_SRC   (OFF_CUR + (size_t)NP * 4)           // E int
#define OFF_BSUM  (OFF_SRC + (size_t)EE * 4)
#define OFF_BOFF  (OFF_BSUM + (size_t)2048)
#define OFF_U     (OFF_BOFF + (size_t)2048)            // Ubt bf16 5*256*128
#define OFF_UB    (OFF_U + (size_t)327680)             // Ub f32 5*256
#define OFF_V     (OFF_UB + (size_t)5120)              // Vbt bf16 4*64*128
#define OFF_GP    (OFF_V + (size_t)65536)              // gpool 64*64 f32
#define OFF_G8    (OFF_GP + (size_t)16384)             // N uint8 (padded)
#define OFF_ZTH   (OFF_G8 + (size_t)500736)            // ztabh bf16 5*100*64
#define OFF_GPART (OFF_ZTH + (size_t)64000)            // 256*4096 f32 = 4 MB
#define WS_NEED   (OFF_GPART + (size_t)4194304)        // ~= 144.2 MB (proven budget 203.8)

extern "C" void kernel_launch(void* const* d_in, const int* in_sizes, int n_in,
                              void* d_out, int out_size, void* d_ws, size_t ws_size,
                              hipStream_t stream) {
  float* out = (float*)d_out;   // reference output is float32 [G,1]
  if (ws_size < WS_NEED) {
    ngnn97_code<<<1, 64, 0, stream>>>(out, 7.0f);
    return;
  }

  const int* z    = (const int*)d_in[0];
  const int* ei   = (const int*)d_in[1];
  const int* n2s  = (const int*)d_in[2];
  const int* s2g  = (const int*)d_in[3];
  const float* ztab = (const float*)d_in[4];
  const float* tfW  = (const float*)d_in[5];
  const float* tfb  = (const float*)d_in[6];
  const float* ggc  = (const float*)d_in[7];
  const float* wih  = (const float*)d_in[8];
  const float* whh  = (const float*)d_in[9];
  const float* bih  = (const float*)d_in[10];
  const float* bhh  = (const float*)d_in[11];
  const float* W1   = (const float*)d_in[12];
  const float* b1   = (const float*)d_in[13];
  const float* W2   = (const float*)d_in[14];
  const float* b2   = (const float*)d_in[15];
  const float* W3   = (const float*)d_in[16];
  const float* b3   = (const float*)d_in[17];

  char* ws = (char*)d_ws;
  unsigned short* xh     = (unsigned short*)(ws + OFF_XH);
  unsigned short* aggx   = (unsigned short*)(ws + OFF_AGG);
  int*            counts = (int*)(ws + OFF_CNT);
  int*            rowp   = (int*)(ws + OFF_ROW);
  int*            curs   = (int*)(ws + OFF_CUR);
  int*            srcs   = (int*)(ws + OFF_SRC);
  int*            bsum   = (int*)(ws + OFF_BSUM);
  int*            boff   = (int*)(ws + OFF_BOFF);
  unsigned short* Ubt    = (unsigned short*)(ws + OFF_U);
  float*          Ub     = (float*)(ws + OFF_UB);
  unsigned short* Vbt    = (unsigned short*)(ws + OFF_V);
  float*          gpool  = (float*)(ws + OFF_GP);
  unsigned char*  g8     = (unsigned char*)(ws + OFF_G8);
  unsigned short* ztabh  = (unsigned short*)(ws + OFF_ZTH);
  float*          gpart  = (float*)(ws + OFF_GPART);

  hipMemsetAsync(counts, 0, (size_t)NP * 4, stream);
  hipMemsetAsync(gpart, 0, (size_t)4194304, stream);

  ngnn97_pre<<<899, 256, 0, stream>>>(ggc, wih, whh, bih, bhh, tfW, ztab, Ubt, Ub, Vbt, ztabh);
  ngnn97_g8<<<(NN + 255) / 256, 256, 0, stream>>>(n2s, s2g, g8);

  // CSR by dst
  const int* srcp = ei;
  const int* dstp = ei + EE;
  ngnn97_hist<<<(EE + 255) / 256, 256, 0, stream>>>(dstp, counts);
  ngnn97_red<<<NBLK, 256, 0, stream>>>(counts, bsum);
  ngnn97_scan1<<<1, 512, 0, stream>>>(bsum, boff);
  ngnn97_scan2<<<NBLK, 256, 0, stream>>>(counts, boff, rowp, curs);
  ngnn97_fill<<<(EE + 255) / 256, 256, 0, stream>>>(srcp, dstp, curs, srcs);
  // after ngnn97_fill, curs[i] == row end

  ngnn97_embed<<<(NN * 16 + 255) / 256, 256, 0, stream>>>(z, ztab, xh);

  for (int l = 0; l < 5; l++) {
    ngnn97_agg<<<(NN + 31) / 32, 256, 0, stream>>>(xh, rowp, curs, srcs, aggx);
    ngnn97_gru<<<(NN + 127) / 128, 256, 0, stream>>>(
        xh, aggx, Ubt + (size_t)l * 32768, Ub + (size_t)l * 256,
        Vbt + (size_t)(l < 4 ? l : 0) * 8192, tfb + (size_t)(l < 4 ? l : 0) * 64,
        z, ztabh + (size_t)(l < 4 ? l + 1 : 0) * 6400, (l < 4) ? 1 : 0);
  }

  ngnn97_pool<<<(NN + 255) / 256, 256, 0, stream>>>(xh, g8, gpart);
  ngnn97_reduce<<<16, 256, 0, stream>>>(gpart, gpool);
  ngnn97_head<<<1, 256, 0, stream>>>(gpool, W1, b1, W2, b2, W3, b3, out);
}

// Round 14
// 1302.005 us; speedup vs baseline: 1.9034x; 1.0542x over previous
//
#include <hip/hip_runtime.h>
#include <hip/hip_bf16.h>

// ---------------- problem constants ----------------
#define NN 500000
#define EE 1250000
#define NP 501760          // padded node count
#define NBLK 489           // scan blocks of 1024

typedef __attribute__((ext_vector_type(8))) short bf16x8;
typedef __attribute__((ext_vector_type(4))) float f32x4;

__device__ __forceinline__ float ngnn97_bf2f(unsigned short u) {
  return __uint_as_float(((unsigned int)u) << 16);
}
__device__ __forceinline__ unsigned short ngnn97_f2bf(float f) {
  union { __hip_bfloat16 b; unsigned short u; } cv;
  cv.b = __float2bfloat16(f);
  return cv.u;
}

// ---------------- diagnostic code writer (guard path only) ----------------
__global__ void ngnn97_code(float* __restrict__ out, float v) {
  if (threadIdx.x < 64) out[threadIdx.x] = v;
}

// ---------------- precompute folded weights (bf16, MFMA-B layout) + bf16 ztab ----------------
__global__ __launch_bounds__(256) void ngnn97_pre(
    const float* __restrict__ ggc, const float* __restrict__ wih,
    const float* __restrict__ whh, const float* __restrict__ bih,
    const float* __restrict__ bhh, const float* __restrict__ tfW,
    const float* __restrict__ ztab,
    unsigned short* __restrict__ Ubt, float* __restrict__ Ub,
    unsigned short* __restrict__ Vbt, unsigned short* __restrict__ ztabh) {
  int idx = blockIdx.x * 256 + threadIdx.x;
  if (idx < 163840) {                      // Ubt: 5*256*128
    int l = idx >> 15, r = idx & 32767;
    int n = r >> 7, k = r & 127;
    float v = 0.f;
    if (k < 64) {
      if (n < 192) {
        const float* gp = ggc + l * 4096 + k * 64;
        const float* wp = wih + l * 12288 + n * 64;
        float acc = 0.f;
#pragma unroll
        for (int t2 = 0; t2 < 64; t2++) acc = fmaf(gp[t2], wp[t2], acc);
        v = acc;
      }
    } else {
      int k2 = k - 64;
      if (n < 128) v = whh[l * 12288 + n * 64 + k2];
      else if (n >= 192) v = whh[l * 12288 + (n - 64) * 64 + k2];
    }
    Ubt[idx] = ngnn97_f2bf(v);
  } else if (idx < 196608) {               // Vbt: 4*64*128 (= tfW flat)
    int i2 = idx - 163840;
    Vbt[i2] = ngnn97_f2bf(tfW[i2]);
  } else if (idx < 197888) {               // Ub: 5*256
    int i2 = idx - 196608;
    int l = i2 >> 8, j = i2 & 255;
    float v;
    if (j < 128)      v = bih[l * 192 + j] + bhh[l * 192 + j];
    else if (j < 192) v = bih[l * 192 + j];
    else              v = bhh[l * 192 + j - 64];
    Ub[i2] = v;
  } else if (idx < 229888) {               // ztabh: 5*100*64 bf16
    int i2 = idx - 197888;
    ztabh[i2] = ngnn97_f2bf(ztab[i2]);
  }
}

// ---------------- CSR build ----------------
__global__ __launch_bounds__(256) void ngnn97_hist(const int* __restrict__ dst, int* __restrict__ counts) {
  int e = blockIdx.x * 256 + threadIdx.x;
  if (e < EE) atomicAdd(&counts[dst[e]], 1);
}

__global__ __launch_bounds__(256) void ngnn97_red(const int* __restrict__ counts, int* __restrict__ bsum) {
  __shared__ int s[256];
  int t = threadIdx.x, base = blockIdx.x * 1024;
  int v = 0;
#pragma unroll
  for (int i = 0; i < 4; i++) v += counts[base + t + i * 256];
  s[t] = v; __syncthreads();
  for (int o = 128; o > 0; o >>= 1) { if (t < o) s[t] += s[t + o]; __syncthreads(); }
  if (t == 0) bsum[blockIdx.x] = s[0];
}

__global__ __launch_bounds__(512) void ngnn97_scan1(const int* __restrict__ bsum, int* __restrict__ boff) {
  __shared__ int s[512];
  int t = threadIdx.x;
  int v = (t < NBLK) ? bsum[t] : 0;
  s[t] = v; __syncthreads();
  for (int o = 1; o < 512; o <<= 1) {
    int a = (t >= o) ? s[t - o] : 0;
    __syncthreads(); s[t] += a; __syncthreads();
  }
  if (t < NBLK) boff[t] = s[t] - v;   // exclusive
}

__global__ __launch_bounds__(256) void ngnn97_scan2(const int* __restrict__ counts, const int* __restrict__ boff,
                                                    int* __restrict__ row_ptr, int* __restrict__ cursor) {
  __shared__ int s[256];
  int t = threadIdx.x, base = blockIdx.x * 1024;
  int4 c = *(const int4*)(counts + base + t * 4);
  int tsum = c.x + c.y + c.z + c.w;
  s[t] = tsum; __syncthreads();
  for (int o = 1; o < 256; o <<= 1) {
    int a = (t >= o) ? s[t - o] : 0;
    __syncthreads(); s[t] += a; __syncthreads();
  }
  int off = boff[blockIdx.x] + s[t] - tsum;
  int4 r;
  r.x = off; r.y = off + c.x; r.z = off + c.x + c.y; r.w = off + c.x + c.y + c.z;
  *(int4*)(row_ptr + base + t * 4) = r;
  *(int4*)(cursor + base + t * 4) = r;
}

__global__ __launch_bounds__(256) void ngnn97_fill(const int* __restrict__ src, const int* __restrict__ dst,
                                                   int* __restrict__ cursor, int* __restrict__ srcs) {
  int e = blockIdx.x * 256 + threadIdx.x;
  if (e < EE) {
    int pos = atomicAdd(&cursor[dst[e]], 1);
    srcs[pos] = src[e];
  }
}

// ---------------- node -> graph id precompute (uint8) ----------------
__global__ __launch_bounds__(256) void ngnn97_g8(const int* __restrict__ n2s, const int* __restrict__ s2g,
                                                 unsigned char* __restrict__ g8) {
  int idx = blockIdx.x * 256 + threadIdx.x;
  if (idx < NN) g8[idx] = (unsigned char)s2g[n2s[idx]];
}

// ---------------- layer-0 embedding: bf16x8 row copies from ztabh ----------------
__global__ __launch_bounds__(256) void ngnn97_embed(const int* __restrict__ z,
                                                    const unsigned short* __restrict__ ztabh,
                                                    unsigned short* __restrict__ xh) {
  int idx = blockIdx.x * 256 + threadIdx.x;
  int node = idx >> 3, sub = idx & 7;
  if (node < NN) {
    int zz = z[node];
    *(bf16x8*)(xh + (size_t)node * 64 + sub * 8) =
        *(const bf16x8*)(ztabh + zz * 64 + sub * 8);
  }
}

// ---------------- neighbor aggregation: 8 nodes/wave, 2-way edge unroll ----------------
__global__ __launch_bounds__(256) void ngnn97_agg(const unsigned short* __restrict__ xh,
                                                  const int* __restrict__ row_ptr,
                                                  const int* __restrict__ row_end, const int* __restrict__ srcs,
                                                  unsigned short* __restrict__ aggx) {
  int t = threadIdx.x;
  int wv = t >> 6, lane = t & 63;
  int grp = lane >> 3, sub = lane & 7;
  int node = blockIdx.x * 32 + wv * 8 + grp;
  if (node >= NN) return;
  int b = row_ptr[node], e = row_end[node];
  float acc[8];
#pragma unroll
  for (int i = 0; i < 8; i++) acc[i] = 0.f;
  int p = b;
  for (; p + 2 <= e; p += 2) {
    int s0 = srcs[p], s1 = srcs[p + 1];
    bf16x8 v0 = *(const bf16x8*)(xh + (size_t)s0 * 64 + sub * 8);
    bf16x8 v1 = *(const bf16x8*)(xh + (size_t)s1 * 64 + sub * 8);
#pragma unroll
    for (int i = 0; i < 8; i++)
      acc[i] += ngnn97_bf2f((unsigned short)v0[i]) + ngnn97_bf2f((unsigned short)v1[i]);
  }
  if (p < e) {
    int s0 = srcs[p];
    bf16x8 v0 = *(const bf16x8*)(xh + (size_t)s0 * 64 + sub * 8);
#pragma unroll
    for (int i = 0; i < 8; i++) acc[i] += ngnn97_bf2f((unsigned short)v0[i]);
  }
  bf16x8 ov;
#pragma unroll
  for (int i = 0; i < 8; i++) ov[i] = (short)ngnn97_f2bf(acc[i]);
  *(bf16x8*)(aggx + (size_t)node * 64 + sub * 8) = ov;
}

// ---------------- GRU via MFMA + next-layer transform (layers 0..3) ----------------
// Block = 128 nodes, 4 waves; wave w owns strip [nbase+32w, +32) -> ZERO barriers.
__global__ __launch_bounds__(256) void ngnn97_gru(
    unsigned short* __restrict__ xh, const unsigned short* __restrict__ aggx,
    const unsigned short* __restrict__ Ubt, const float* __restrict__ Ub,
    const unsigned short* __restrict__ Vbt, const float* __restrict__ tfb,
    const int* __restrict__ z, const unsigned short* __restrict__ ztabh) {
  __shared__ unsigned short Abuf[128 * 72];    // xh strip staging + xn scratch, 18.4 KB
  const int t = threadIdx.x;
  const int lane = t & 63, w = t >> 6;
  const int ncol = lane & 15, quad = lane >> 4;
  const int nbase = blockIdx.x * 128;
  const int strip = 32 * w;

  // ---- stage xh strip rows -> Abuf cols 0..63 (strip-local) ----
#pragma unroll
  for (int i = 0; i < 8; i++) {
    int chunk = i * 64 + lane;                 // 512 = 32 rows x 16 ushort4
    int r2 = chunk >> 4, c4 = (chunk & 15) << 2;
    int node = nbase + strip + r2;
    ushort4 qx = make_ushort4(0, 0, 0, 0);
    if (node < NN) qx = *(const ushort4*)(xh + (size_t)node * 64 + c4);
    *(ushort4*)(Abuf + (strip + r2) * 72 + c4) = qx;
  }

  // ---- A-frags: aggx half direct-global, xh half from LDS ----
  bf16x8 afrA[2][2], afrX[2][2];
#pragma unroll
  for (int mm = 0; mm < 2; mm++) {
    int node = nbase + strip + mm * 16 + ncol;
#pragma unroll
    for (int kc = 0; kc < 2; kc++) {
      bf16x8 va = (bf16x8){0, 0, 0, 0, 0, 0, 0, 0};
      if (node < NN) va = *(const bf16x8*)(aggx + (size_t)node * 64 + quad * 8 + kc * 32);
      afrA[mm][kc] = va;
      afrX[mm][kc] = *(const bf16x8*)(Abuf + (strip + mm * 16 + ncol) * 72 + quad * 8 + kc * 32);
    }
  }

  // ---- gate GEMM + GRU update; xn overwrites Abuf cols 0..63 ----
#pragma unroll
  for (int c = 0; c < 4; c++) {
    f32x4 aR[2], aZ[2], aN[2], aH[2];
#pragma unroll
    for (int mm = 0; mm < 2; mm++) {
      aR[mm] = (f32x4){0.f, 0.f, 0.f, 0.f}; aZ[mm] = aR[mm];
      aN[mm] = aR[mm]; aH[mm] = aR[mm];
    }
#pragma unroll
    for (int kc = 0; kc < 4; kc++) {
      const unsigned short* ub = Ubt + (size_t)(c * 16 + ncol) * 128 + quad * 8 + kc * 32;
      bf16x8 bR = *(const bf16x8*)(ub);
      bf16x8 bZ = *(const bf16x8*)(ub + 64 * 128);
      bf16x8 bX = (kc < 2) ? *(const bf16x8*)(ub + 128 * 128)
                           : *(const bf16x8*)(ub + 192 * 128);
#pragma unroll
      for (int mm = 0; mm < 2; mm++) {
        bf16x8 a = (kc < 2) ? afrA[mm][kc] : afrX[mm][kc - 2];
        aR[mm] = __builtin_amdgcn_mfma_f32_16x16x32_bf16(a, bR, aR[mm], 0, 0, 0);
        aZ[mm] = __builtin_amdgcn_mfma_f32_16x16x32_bf16(a, bZ, aZ[mm], 0, 0, 0);
        if (kc < 2) aN[mm] = __builtin_amdgcn_mfma_f32_16x16x32_bf16(a, bX, aN[mm], 0, 0, 0);
        else        aH[mm] = __builtin_amdgcn_mfma_f32_16x16x32_bf16(a, bX, aH[mm], 0, 0, 0);
      }
    }
    int j = c * 16 + ncol;
    float bRs = Ub[j], bZs = Ub[64 + j], bNs = Ub[128 + j], bHs = Ub[192 + j];
#pragma unroll
    for (int mm = 0; mm < 2; mm++)
#pragma unroll
      for (int r = 0; r < 4; r++) {
        int row = strip + mm * 16 + quad * 4 + r;
        float R = aR[mm][r] + bRs, Z = aZ[mm][r] + bZs;
        float Nv = aN[mm][r] + bNs, H = aH[mm][r] + bHs;
        float rg = 1.f / (1.f + __expf(-R));
        float ug = 1.f / (1.f + __expf(-Z));
        float e2 = __expf(2.f * (Nv + rg * H));
        float nn2 = 1.f - 2.f / (e2 + 1.f);    // tanh via fast exp (saturates safely)
        float xo = ngnn97_bf2f(Abuf[row * 72 + j]);
        Abuf[row * 72 + j] = ngnn97_f2bf((1.f - ug) * nn2 + ug * xo);
      }
  }

  // ---- A2-frags: xn from LDS, ze direct from bf16 ztab ----
  bf16x8 afrN[2][2], afrE[2][2];
#pragma unroll
  for (int mm = 0; mm < 2; mm++) {
    int node = nbase + strip + mm * 16 + ncol;
    int zz = (node < NN) ? z[node] : 0;
#pragma unroll
    for (int kc = 0; kc < 2; kc++) {
      afrN[mm][kc] = *(const bf16x8*)(Abuf + (strip + mm * 16 + ncol) * 72 + quad * 8 + kc * 32);
      afrE[mm][kc] = *(const bf16x8*)(ztabh + zz * 64 + quad * 8 + kc * 32);
    }
  }
  // ---- transform GEMM -> Abuf cols 0..63 ----
#pragma unroll
  for (int c2 = 0; c2 < 4; c2++) {
    f32x4 acc[2];
    acc[0] = (f32x4){0.f, 0.f, 0.f, 0.f}; acc[1] = acc[0];
#pragma unroll
    for (int kc = 0; kc < 4; kc++) {
      bf16x8 bV = *(const bf16x8*)(Vbt + (size_t)(c2 * 16 + ncol) * 128 + quad * 8 + kc * 32);
#pragma unroll
      for (int mm = 0; mm < 2; mm++) {
        bf16x8 a = (kc < 2) ? afrN[mm][kc] : afrE[mm][kc - 2];
        acc[mm] = __builtin_amdgcn_mfma_f32_16x16x32_bf16(a, bV, acc[mm], 0, 0, 0);
      }
    }
    int j = c2 * 16 + ncol;
    float bt = tfb[j];
#pragma unroll
    for (int mm = 0; mm < 2; mm++)
#pragma unroll
      for (int r = 0; r < 4; r++) {
        int row = strip + mm * 16 + quad * 4 + r;
        Abuf[row * 72 + j] = ngnn97_f2bf(acc[mm][r] + bt);
      }
  }

  // ---- coalesced store: Abuf cols 0..63 (strip) -> xh ----
#pragma unroll
  for (int i = 0; i < 8; i++) {
    int chunk = i * 64 + lane;
    int r2 = chunk >> 4, c4 = (chunk & 15) << 2;
    int node = nbase + strip + r2;
    if (node < NN)
      *(ushort4*)(xh + (size_t)node * 64 + c4) = *(const ushort4*)(Abuf + (strip + r2) * 72 + c4);
  }
}

// ---------------- final layer: GRU (no transform) + FUSED POOLING ----------------
// xn never goes back to HBM; pooled into gacc (LDS) then flushed to gpart slots.
__global__ __launch_bounds__(256) void ngnn97_gru5(
    const unsigned short* __restrict__ xh, const unsigned short* __restrict__ aggx,
    const unsigned short* __restrict__ Ubt, const float* __restrict__ Ub,
    const unsigned char* __restrict__ g8, float* __restrict__ gpart) {
  __shared__ unsigned short Abuf[128 * 72];    // 18.4 KB
  __shared__ float gacc[4096];                 // 16 KB
  const int t = threadIdx.x;
  const int lane = t & 63, w = t >> 6;
  const int ncol = lane & 15, quad = lane >> 4;
  const int nbase = blockIdx.x * 128;
  const int strip = 32 * w;

  // zero gacc (barrier below covers completion)
  for (int i = t; i < 4096; i += 256) gacc[i] = 0.f;

  // stage xh strip rows -> Abuf cols 0..63
#pragma unroll
  for (int i = 0; i < 8; i++) {
    int chunk = i * 64 + lane;
    int r2 = chunk >> 4, c4 = (chunk & 15) << 2;
    int node = nbase + strip + r2;
    ushort4 qx = make_ushort4(0, 0, 0, 0);
    if (node < NN) qx = *(const ushort4*)(xh + (size_t)node * 64 + c4);
    *(ushort4*)(Abuf + (strip + r2) * 72 + c4) = qx;
  }
  __syncthreads();   // gacc zero-init complete block-wide

  bf16x8 afrA[2][2], afrX[2][2];
#pragma unroll
  for (int mm = 0; mm < 2; mm++) {
    int node = nbase + strip + mm * 16 + ncol;
#pragma unroll
    for (int kc = 0; kc < 2; kc++) {
      bf16x8 va = (bf16x8){0, 0, 0, 0, 0, 0, 0, 0};
      if (node < NN) va = *(const bf16x8*)(aggx + (size_t)node * 64 + quad * 8 + kc * 32);
      afrA[mm][kc] = va;
      afrX[mm][kc] = *(const bf16x8*)(Abuf + (strip + mm * 16 + ncol) * 72 + quad * 8 + kc * 32);
    }
  }

#pragma unroll
  for (int c = 0; c < 4; c++) {
    f32x4 aR[2], aZ[2], aN[2], aH[2];
#pragma unroll
    for (int mm = 0; mm < 2; mm++) {
      aR[mm] = (f32x4){0.f, 0.f, 0.f, 0.f}; aZ[mm] = aR[mm];
      aN[mm] = aR[mm]; aH[mm] = aR[mm];
    }
#pragma unroll
    for (int kc = 0; kc < 4; kc++) {
      const unsigned short* ub = Ubt + (size_t)(c * 16 + ncol) * 128 + quad * 8 + kc * 32;
      bf16x8 bR = *(const bf16x8*)(ub);
      bf16x8 bZ = *(const bf16x8*)(ub + 64 * 128);
      bf16x8 bX = (kc < 2) ? *(const bf16x8*)(ub + 128 * 128)
                           : *(const bf16x8*)(ub + 192 * 128);
#pragma unroll
      for (int mm = 0; mm < 2; mm++) {
        bf16x8 a = (kc < 2) ? afrA[mm][kc] : afrX[mm][kc - 2];
        aR[mm] = __builtin_amdgcn_mfma_f32_16x16x32_bf16(a, bR, aR[mm], 0, 0, 0);
        aZ[mm] = __builtin_amdgcn_mfma_f32_16x16x32_bf16(a, bZ, aZ[mm], 0, 0, 0);
        if (kc < 2) aN[mm] = __builtin_amdgcn_mfma_f32_16x16x32_bf16(a, bX, aN[mm], 0, 0, 0);
        else        aH[mm] = __builtin_amdgcn_mfma_f32_16x16x32_bf16(a, bX, aH[mm], 0, 0, 0);
      }
    }
    int j = c * 16 + ncol;
    float bRs = Ub[j], bZs = Ub[64 + j], bNs = Ub[128 + j], bHs = Ub[192 + j];
#pragma unroll
    for (int mm = 0; mm < 2; mm++)
#pragma unroll
      for (int r = 0; r < 4; r++) {
        int row = strip + mm * 16 + quad * 4 + r;
        float R = aR[mm][r] + bRs, Z = aZ[mm][r] + bZs;
        float Nv = aN[mm][r] + bNs, H = aH[mm][r] + bHs;
        float rg = 1.f / (1.f + __expf(-R));
        float ug = 1.f / (1.f + __expf(-Z));
        float e2 = __expf(2.f * (Nv + rg * H));
        float nn2 = 1.f - 2.f / (e2 + 1.f);
        float xo = ngnn97_bf2f(Abuf[row * 72 + j]);
        Abuf[row * 72 + j] = ngnn97_f2bf((1.f - ug) * nn2 + ug * xo);
      }
  }

  // ---- fused pooling: add strip rows (bf16 xn) into block-shared gacc ----
  for (int i = 0; i < 32; i++) {
    int node = nbase + strip + i;
    if (node < NN) {
      int g = g8[node];
      atomicAdd(&gacc[g * 64 + lane], ngnn97_bf2f(Abuf[(strip + i) * 72 + lane]));
    }
  }
  __syncthreads();
  float* slot = gpart + (size_t)(blockIdx.x & 255) * 4096;
  for (int i = t; i < 4096; i += 256) {
    float v = gacc[i];
    if (v != 0.f) atomicAdd(&slot[i], v);
  }
}

// ---------------- pooling stage 2: fold 256 slots -> gpool ----------------
__global__ __launch_bounds__(256) void ngnn97_reduce(const float* __restrict__ gpart,
                                                     float* __restrict__ gpool) {
  int i = blockIdx.x * 256 + threadIdx.x;    // 0..4095
  float s = 0.f;
#pragma unroll 8
  for (int k = 0; k < 256; k++) s += gpart[(size_t)k * 4096 + i];
  gpool[i] = s;
}

// ---------------- MLP head (output: float32 [G,1]) ----------------
__global__ __launch_bounds__(256) void ngnn97_head(
    const float* __restrict__ gpool,
    const float* __restrict__ W1, const float* __restrict__ b1,
    const float* __restrict__ W2, const float* __restrict__ b2,
    const float* __restrict__ W3, const float* __restrict__ b3,
    float* __restrict__ out) {
  __shared__ float gp[4096];
  __shared__ float h1[2048];
  __shared__ float h2[1024];
  int t = threadIdx.x;
  for (int i = t; i < 4096; i += 256) gp[i] = gpool[i];
  __syncthreads();
  for (int i = t; i < 2048; i += 256) {
    int g = i >> 5, o = i & 31;
    float a = b1[o];
    for (int d = 0; d < 64; d++) a = fmaf(gp[g * 64 + d], W1[o * 64 + d], a);
    h1[i] = (a > 0.f) ? a : (__expf(a) - 1.f);
  }
  __syncthreads();
  for (int i = t; i < 1024; i += 256) {
    int g = i >> 4, o = i & 15;
    float a = b2[o];
    for (int d = 0; d < 32; d++) a = fmaf(h1[g * 32 + d], W2[o * 32 + d], a);
    h2[i] = (a > 0.f) ? a : (__expf(a) - 1.f);
  }
  __syncthreads();
  if (t < 64) {
    float a = b3[0];
    for (int d = 0; d < 16; d++) a = fmaf(h2[t * 16 + d], W3[d], a);
    out[t] = a;
  }
}

// ---------------- workspace layout (byte offsets) ----------------
#define OFF_XH    ((size_t)0)                          // N*64 bf16 = 64,000,000
#define OFF_AGG   ((size_t)64000000)                   // N*64 bf16 = 64,000,000
#define OFF_CNT   ((size_t)128000000)                  // NP int
#define OFF_ROW   (OFF_CNT + (size_t)NP * 4)
#define OFF_CUR   (OFF_ROW + (size_t)NP * 4)
#define OFF_SRC   (OFF_CUR + (size_t)NP * 4)           // E int
#define OFF_BSUM  (OFF_SRC + (size_t)EE * 4)
#define OFF_BOFF  (OFF_BSUM + (size_t)2048)
#define OFF_U     (OFF_BOFF + (size_t)2048)            // Ubt bf16 5*256*128
#define OFF_UB    (OFF_U + (size_t)327680)             // Ub f32 5*256
#define OFF_V     (OFF_UB + (size_t)5120)              // Vbt bf16 4*64*128
#define OFF_GP    (OFF_V + (size_t)65536)              // gpool 64*64 f32
#define OFF_G8    (OFF_GP + (size_t)16384)             // N uint8 (padded)
#define OFF_ZTH   (OFF_G8 + (size_t)500736)            // ztabh bf16 5*100*64
#define OFF_GPART (OFF_ZTH + (size_t)64000)            // 256*4096 f32 = 4 MB
#define WS_NEED   (OFF_GPART + (size_t)4194304)        // ~= 144.2 MB (proven budget 203.8)

extern "C" void kernel_launch(void* const* d_in, const int* in_sizes, int n_in,
                              void* d_out, int out_size, void* d_ws, size_t ws_size,
                              hipStream_t stream) {
  float* out = (float*)d_out;   // reference output is float32 [G,1]
  if (ws_size < WS_NEED) {
    ngnn97_code<<<1, 64, 0, stream>>>(out, 7.0f);
    return;
  }

  const int* z    = (const int*)d_in[0];
  const int* ei   = (const int*)d_in[1];
  const int* n2s  = (const int*)d_in[2];
  const int* s2g  = (const int*)d_in[3];
  const float* ztab = (const float*)d_in[4];
  const float* tfW  = (const float*)d_in[5];
  const float* tfb  = (const float*)d_in[6];
  const float* ggc  = (const float*)d_in[7];
  const float* wih  = (const float*)d_in[8];
  const float* whh  = (const float*)d_in[9];
  const float* bih  = (const float*)d_in[10];
  const float* bhh  = (const float*)d_in[11];
  const float* W1   = (const float*)d_in[12];
  const float* b1   = (const float*)d_in[13];
  const float* W2   = (const float*)d_in[14];
  const float* b2   = (const float*)d_in[15];
  const float* W3   = (const float*)d_in[16];
  const float* b3   = (const float*)d_in[17];

  char* ws = (char*)d_ws;
  unsigned short* xh     = (unsigned short*)(ws + OFF_XH);
  unsigned short* aggx   = (unsigned short*)(ws + OFF_AGG);
  int*            counts = (int*)(ws + OFF_CNT);
  int*            rowp   = (int*)(ws + OFF_ROW);
  int*            curs   = (int*)(ws + OFF_CUR);
  int*            srcs   = (int*)(ws + OFF_SRC);
  int*            bsum   = (int*)(ws + OFF_BSUM);
  int*            boff   = (int*)(ws + OFF_BOFF);
  unsigned short* Ubt    = (unsigned short*)(ws + OFF_U);
  float*          Ub     = (float*)(ws + OFF_UB);
  unsigned short* Vbt    = (unsigned short*)(ws + OFF_V);
  float*          gpool  = (float*)(ws + OFF_GP);
  unsigned char*  g8     = (unsigned char*)(ws + OFF_G8);
  unsigned short* ztabh  = (unsigned short*)(ws + OFF_ZTH);
  float*          gpart  = (float*)(ws + OFF_GPART);

  hipMemsetAsync(counts, 0, (size_t)NP * 4, stream);
  hipMemsetAsync(gpart, 0, (size_t)4194304, stream);

  ngnn97_pre<<<899, 256, 0, stream>>>(ggc, wih, whh, bih, bhh, tfW, ztab, Ubt, Ub, Vbt, ztabh);
  ngnn97_g8<<<(NN + 255) / 256, 256, 0, stream>>>(n2s, s2g, g8);

  // CSR by dst
  const int* srcp = ei;
  const int* dstp = ei + EE;
  ngnn97_hist<<<(EE + 255) / 256, 256, 0, stream>>>(dstp, counts);
  ngnn97_red<<<NBLK, 256, 0, stream>>>(counts, bsum);
  ngnn97_scan1<<<1, 512, 0, stream>>>(bsum, boff);
  ngnn97_scan2<<<NBLK, 256, 0, stream>>>(counts, boff, rowp, curs);
  ngnn97_fill<<<(EE + 255) / 256, 256, 0, stream>>>(srcp, dstp, curs, srcs);
  // after ngnn97_fill, curs[i] == row end

  ngnn97_embed<<<(NN * 8 + 255) / 256, 256, 0, stream>>>(z, ztabh, xh);

  for (int l = 0; l < 4; l++) {
    ngnn97_agg<<<(NN + 31) / 32, 256, 0, stream>>>(xh, rowp, curs, srcs, aggx);
    ngnn97_gru<<<(NN + 127) / 128, 256, 0, stream>>>(
        xh, aggx, Ubt + (size_t)l * 32768, Ub + (size_t)l * 256,
        Vbt + (size_t)l * 8192, tfb + (size_t)l * 64,
        z, ztabh + (size_t)(l + 1) * 6400);
  }
  // final layer: GRU + fused pooling (xn never written to HBM)
  ngnn97_agg<<<(NN + 31) / 32, 256, 0, stream>>>(xh, rowp, curs, srcs, aggx);
  ngnn97_gru5<<<(NN + 127) / 128, 256, 0, stream>>>(
      xh, aggx, Ubt + (size_t)4 * 32768, Ub + (size_t)4 * 256, g8, gpart);

  ngnn97_reduce<<<16, 256, 0, stream>>>(gpart, gpool);
  ngnn97_head<<<1, 256, 0, stream>>>(gpool, W1, b1, W2, b2, W3, b3, out);
}